// Round 3
// baseline (5141.627 us; speedup 1.0000x reference)
//
#include <hip/hip_runtime.h>
#include <math.h>

#define BB 16
#define QQ 900
#define CC 91
#define TT 100
#define BT (BB * TT)        // 1600
#define NTHREADS 256
#define NSLOT 15            // ceil(900/64)

__device__ __forceinline__ unsigned ordkey(float f) {
    unsigned u = __float_as_uint(f);
    return (u & 0x80000000u) ? ~u : (u | 0x80000000u);
}

__device__ __forceinline__ unsigned long long u64min(unsigned long long a, unsigned long long b) {
    return a < b ? a : b;
}

// pack (key, row, col) -> u64, lexicographic order == numpy flat argmin order
__device__ __forceinline__ unsigned long long packkrc(unsigned key, int row, int col) {
    return ((unsigned long long)key << 21) | ((unsigned long long)row << 11) | (unsigned)col;
}

// ---------------------------------------------------------------------------
// Kernel 1: cost[b,q,j] for j in [0, B*T)   (unchanged — verified correct)
// ---------------------------------------------------------------------------
__global__ __launch_bounds__(NTHREADS) void cost_kernel(
    const float* __restrict__ logits,
    const float* __restrict__ pred,
    const int*   __restrict__ tlab,
    const float* __restrict__ tbox,
    float*       __restrict__ cost)
{
    const int bq = blockIdx.x;
    __shared__ float sig[CC];

    const float* lg = logits + (size_t)bq * CC;
    for (int c = threadIdx.x; c < CC; c += NTHREADS) {
        float x = lg[c];
        sig[c] = 1.0f / (1.0f + expf(-x));
    }

    const float4 p = *(const float4*)(pred + (size_t)bq * 4);
    const float p_x0 = p.x - 0.5f * p.z;
    const float p_y0 = p.y - 0.5f * p.w;
    const float p_x1 = p.x + 0.5f * p.z;
    const float p_y1 = p.y + 0.5f * p.w;
    const float area1 = (p_x1 - p_x0) * (p_y1 - p_y0);

    __syncthreads();

    float* crow = cost + (size_t)bq * BT;
    for (int j = threadIdx.x; j < BT; j += NTHREADS) {
        float4 t = *(const float4*)(tbox + (size_t)j * 4);
        int id = tlab[j];
        float cclass = -sig[id];
        float cbbox = ((fabsf(p.x - t.x) + fabsf(p.y - t.y)) + fabsf(p.z - t.z)) + fabsf(p.w - t.w);

        float t_x0 = t.x - 0.5f * t.z, t_y0 = t.y - 0.5f * t.w;
        float t_x1 = t.x + 0.5f * t.z, t_y1 = t.y + 0.5f * t.w;
        float area2 = (t_x1 - t_x0) * (t_y1 - t_y0);

        float ltx = fmaxf(p_x0, t_x0), lty = fmaxf(p_y0, t_y0);
        float rbx = fminf(p_x1, t_x1), rby = fminf(p_y1, t_y1);
        float iw = fmaxf(rbx - ltx, 0.0f), ih = fmaxf(rby - lty, 0.0f);
        float inter = iw * ih;
        float uni = (area1 + area2) - inter;
        float iou = inter / uni;

        float ex0 = fminf(p_x0, t_x0), ey0 = fminf(p_y0, t_y0);
        float ex1 = fmaxf(p_x1, t_x1), ey1 = fmaxf(p_y1, t_y1);
        float ew = fmaxf(ex1 - ex0, 0.0f), eh = fmaxf(ey1 - ey0, 0.0f);
        float ae = ew * eh;
        float giou = iou - (ae - uni) / ae;

        crow[j] = (cbbox + cclass) + (-giou);
    }
}

// ---------------------------------------------------------------------------
// Kernel 2: greedy matcher. Phase 1: 4 waves scan row minima -> LDS.
// Phase 2: SINGLE WAVE runs all 100 steps, per-row state in registers
// (15 u64 slots/lane), no __syncthreads in the loop.
// ---------------------------------------------------------------------------
__global__ __launch_bounds__(NTHREADS) void greedy_kernel(
    const float* __restrict__ cost,
    float*       __restrict__ rows_out,
    float*       __restrict__ cols_out)
{
    const int b = blockIdx.x;
    const float* cb = cost + (size_t)b * QQ * BT;

    __shared__ unsigned long long rowpack[QQ];  // packed (key,row,col) per row
    __shared__ unsigned colok[TT + 4];          // ~0u = valid, 0 = removed (u32 for b128 reads)

    const int tid = threadIdx.x;
    if (tid < TT + 4) colok[tid] = (tid < TT) ? 0xFFFFFFFFu : 0u;

    // ---- phase 1: all 256 threads compute initial row minima ----
    for (int r = tid; r < QQ; r += NTHREADS) {
        const float* row = cb + (size_t)r * BT;
        unsigned long long best = ~0ULL;
        for (int c4 = 0; c4 < TT / 4; ++c4) {
            float4 v = *(const float4*)(row + c4 * 4);
            int c0 = c4 * 4;
            best = u64min(best, packkrc(ordkey(v.x), r, c0 + 0));
            best = u64min(best, packkrc(ordkey(v.y), r, c0 + 1));
            best = u64min(best, packkrc(ordkey(v.z), r, c0 + 2));
            best = u64min(best, packkrc(ordkey(v.w), r, c0 + 3));
        }
        rowpack[r] = best;
    }
    __syncthreads();
    if (tid >= 64) return;          // only wave 0 continues; no more barriers

    const int lane = tid;
    unsigned long long slot[NSLOT];
    #pragma unroll
    for (int i = 0; i < NSLOT; ++i) {
        int r = i * 64 + lane;
        slot[i] = (r < QQ) ? rowpack[r] : ~0ULL;
    }

    for (int step = 0; step < TT; ++step) {
        // ---- lane-local min over register slots ----
        unsigned long long m = slot[0];
        #pragma unroll
        for (int i = 1; i < NSLOT; ++i) m = u64min(m, slot[i]);

        // ---- wave butterfly min: all lanes get global min ----
        #pragma unroll
        for (int off = 1; off < 64; off <<= 1)
            m = u64min(m, __shfl_xor(m, off, 64));

        const int rstar = (int)((m >> 11) & 0x3FF);
        const int cstar = (int)(m & 0x7FF);

        if (lane == 0) {
            rows_out[b * TT + step] = (float)rstar;
            cols_out[b * TT + step] = (float)cstar;
            colok[cstar] = 0u;      // same-wave DS ordering guarantees visibility
        }

        // ---- remove matched row (static-unrolled slot select) ----
        if (lane == (rstar & 63)) {
            const int si = rstar >> 6;
            #pragma unroll
            for (int i = 0; i < NSLOT; ++i)
                if (i == si) slot[i] = ~0ULL;
        }

        // ---- rescan rows whose cached min-col was just removed ----
        #pragma unroll
        for (int i = 0; i < NSLOT; ++i) {
            if ((int)(slot[i] & 0x7FF) == cstar && slot[i] != ~0ULL) {
                const int r = i * 64 + lane;
                const float* row = cb + (size_t)r * BT;
                unsigned long long best = ~0ULL;
                for (int c4 = 0; c4 < TT / 4; ++c4) {   // rolled: keep code small
                    float4 v = *(const float4*)(row + c4 * 4);
                    uint4 ok = *(const uint4*)(&colok[c4 * 4]);
                    int c0 = c4 * 4;
                    best = u64min(best, packkrc(ordkey(v.x) | ~ok.x, r, c0 + 0));
                    best = u64min(best, packkrc(ordkey(v.y) | ~ok.y, r, c0 + 1));
                    best = u64min(best, packkrc(ordkey(v.z) | ~ok.z, r, c0 + 2));
                    best = u64min(best, packkrc(ordkey(v.w) | ~ok.w, r, c0 + 3));
                }
                slot[i] = best;
            }
        }
    }
}

extern "C" void kernel_launch(void* const* d_in, const int* in_sizes, int n_in,
                              void* d_out, int out_size, void* d_ws, size_t ws_size,
                              hipStream_t stream) {
    const float* logits = (const float*)d_in[0];   // [16,900,91]
    const float* pred   = (const float*)d_in[1];   // [16,900,4]
    const int*   tlab   = (const int*)d_in[2];     // [16,100]
    const float* tbox   = (const float*)d_in[3];   // [16,100,4]

    float* out = (float*)d_out;
    float* cost = out;                              // 23,040,000
    float* rows = out + (size_t)BB * QQ * BT;       // 1600
    float* cols = rows + (size_t)BB * TT;           // 1600

    cost_kernel<<<BB * QQ, NTHREADS, 0, stream>>>(logits, pred, tlab, tbox, cost);
    greedy_kernel<<<BB, NTHREADS, 0, stream>>>(cost, rows, cols);
}

// Round 4
// 1569.857 us; speedup vs baseline: 3.2752x; 3.2752x over previous
//
#include <hip/hip_runtime.h>
#include <math.h>

#define BB 16
#define QQ 900
#define CC 91
#define TT 100
#define BT (BB * TT)        // 1600
#define NTHREADS 256
#define NSLOT 15            // ceil(900/64)

__device__ __forceinline__ unsigned ordkey(float f) {
    unsigned u = __float_as_uint(f);
    return (u & 0x80000000u) ? ~u : (u | 0x80000000u);
}

__device__ __forceinline__ unsigned long long u64min(unsigned long long a, unsigned long long b) {
    return a < b ? a : b;
}

// pack (key, row, col) -> u64; lexicographic order == numpy flat argmin order
__device__ __forceinline__ unsigned long long packkrc(unsigned key, int row, int col) {
    return ((unsigned long long)key << 21) | ((unsigned long long)row << 11) | (unsigned)col;
}

// ---------------------------------------------------------------------------
// Kernel 1: cost[b,q,j] for j in [0, B*T)   (unchanged — verified correct)
// ---------------------------------------------------------------------------
__global__ __launch_bounds__(NTHREADS) void cost_kernel(
    const float* __restrict__ logits,
    const float* __restrict__ pred,
    const int*   __restrict__ tlab,
    const float* __restrict__ tbox,
    float*       __restrict__ cost)
{
    const int bq = blockIdx.x;
    __shared__ float sig[CC];

    const float* lg = logits + (size_t)bq * CC;
    for (int c = threadIdx.x; c < CC; c += NTHREADS) {
        float x = lg[c];
        sig[c] = 1.0f / (1.0f + expf(-x));
    }

    const float4 p = *(const float4*)(pred + (size_t)bq * 4);
    const float p_x0 = p.x - 0.5f * p.z;
    const float p_y0 = p.y - 0.5f * p.w;
    const float p_x1 = p.x + 0.5f * p.z;
    const float p_y1 = p.y + 0.5f * p.w;
    const float area1 = (p_x1 - p_x0) * (p_y1 - p_y0);

    __syncthreads();

    float* crow = cost + (size_t)bq * BT;
    for (int j = threadIdx.x; j < BT; j += NTHREADS) {
        float4 t = *(const float4*)(tbox + (size_t)j * 4);
        int id = tlab[j];
        float cclass = -sig[id];
        float cbbox = ((fabsf(p.x - t.x) + fabsf(p.y - t.y)) + fabsf(p.z - t.z)) + fabsf(p.w - t.w);

        float t_x0 = t.x - 0.5f * t.z, t_y0 = t.y - 0.5f * t.w;
        float t_x1 = t.x + 0.5f * t.z, t_y1 = t.y + 0.5f * t.w;
        float area2 = (t_x1 - t_x0) * (t_y1 - t_y0);

        float ltx = fmaxf(p_x0, t_x0), lty = fmaxf(p_y0, t_y0);
        float rbx = fminf(p_x1, t_x1), rby = fminf(p_y1, t_y1);
        float iw = fmaxf(rbx - ltx, 0.0f), ih = fmaxf(rby - lty, 0.0f);
        float inter = iw * ih;
        float uni = (area1 + area2) - inter;
        float iou = inter / uni;

        float ex0 = fminf(p_x0, t_x0), ey0 = fminf(p_y0, t_y0);
        float ex1 = fmaxf(p_x1, t_x1), ey1 = fmaxf(p_y1, t_y1);
        float ew = fmaxf(ex1 - ex0, 0.0f), eh = fmaxf(ey1 - ey0, 0.0f);
        float ae = ew * eh;
        float giou = iou - (ae - uni) / ae;

        crow[j] = (cbbox + cclass) + (-giou);
    }
}

// ---------------------------------------------------------------------------
// Kernel 2: greedy matcher. Phase 1: 4 waves -> initial row minima in LDS.
// Phase 2: single wave, all state in registers:
//   slot[15] : per-lane packed (key,row,col) row minima
//   cm0,cm1  : 128-bit column-validity mask replicated per lane
// Rescans run CONCURRENTLY across lanes (pend bitmask + ballot loop),
// inner 25x float4 loads fully unrolled (all in flight).
// ---------------------------------------------------------------------------
__global__ __launch_bounds__(NTHREADS, 1) void greedy_kernel(
    const float* __restrict__ cost,
    float*       __restrict__ rows_out,
    float*       __restrict__ cols_out)
{
    const int b = blockIdx.x;
    const float* cb = cost + (size_t)b * QQ * BT;

    __shared__ unsigned long long rowpack[QQ];

    const int tid = threadIdx.x;

    // ---- phase 1: 256 threads compute initial row minima (cols 0..99) ----
    for (int r = tid; r < QQ; r += NTHREADS) {
        const float* row = cb + (size_t)r * BT;
        unsigned long long best = ~0ULL;
        #pragma unroll
        for (int c4 = 0; c4 < TT / 4; ++c4) {
            float4 v = *(const float4*)(row + c4 * 4);
            int c0 = c4 * 4;
            best = u64min(best, packkrc(ordkey(v.x), r, c0 + 0));
            best = u64min(best, packkrc(ordkey(v.y), r, c0 + 1));
            best = u64min(best, packkrc(ordkey(v.z), r, c0 + 2));
            best = u64min(best, packkrc(ordkey(v.w), r, c0 + 3));
        }
        rowpack[r] = best;
    }
    __syncthreads();
    if (tid >= 64) return;          // single wave from here on; no more barriers

    const int lane = tid;
    unsigned long long slot[NSLOT];
    #pragma unroll
    for (int i = 0; i < NSLOT; ++i) {
        int r = i * 64 + lane;
        slot[i] = (r < QQ) ? rowpack[r] : ~0ULL;
    }

    // column validity bitmask (cols 0..99 valid), replicated per lane
    unsigned long long cm0 = ~0ULL;
    unsigned long long cm1 = (1ULL << (TT - 64)) - 1;   // cols 64..99

    for (int step = 0; step < TT; ++step) {
        // ---- lane-local min over register slots ----
        unsigned long long m = slot[0];
        #pragma unroll
        for (int i = 1; i < NSLOT; ++i) m = u64min(m, slot[i]);

        // ---- wave butterfly min: all lanes get global min ----
        #pragma unroll
        for (int off = 1; off < 64; off <<= 1)
            m = u64min(m, __shfl_xor(m, off, 64));

        const int rstar = (int)((m >> 11) & 0x3FF);
        const int cstar = (int)(m & 0x7FF);

        if (lane == 0) {
            rows_out[b * TT + step] = (float)rstar;
            cols_out[b * TT + step] = (float)cstar;
        }

        // remove matched column from replicated mask (cstar is wave-uniform)
        if (cstar < 64) cm0 &= ~(1ULL << cstar);
        else            cm1 &= ~(1ULL << (cstar - 64));

        // remove matched row
        if (lane == (rstar & 63)) {
            const int si = rstar >> 6;
            #pragma unroll
            for (int i = 0; i < NSLOT; ++i)
                if (i == si) slot[i] = ~0ULL;
        }

        // ---- build per-lane pending mask: rows whose cached min-col died ----
        unsigned pend = 0;
        #pragma unroll
        for (int i = 0; i < NSLOT; ++i)
            if ((int)(slot[i] & 0x7FF) == cstar) pend |= (1u << i);

        // ---- concurrent rescans: all pending lanes at once ----
        while (__ballot(pend != 0)) {
            if (pend) {
                const int i = __ffs((int)pend) - 1;
                pend &= pend - 1;
                const int r = i * 64 + lane;
                const float* row = cb + (size_t)r * BT;
                unsigned long long best = ~0ULL;
                #pragma unroll
                for (int c4 = 0; c4 < TT / 4; ++c4) {
                    float4 v = *(const float4*)(row + c4 * 4);
                    const int c0 = c4 * 4;
                    // constant c -> mask bit test folds to a shift+and
                    unsigned k0 = ((unsigned)(((c0 + 0) < 64 ? cm0 : cm1) >> ((c0 + 0) & 63)) & 1u) ? ordkey(v.x) : 0xFFFFFFFFu;
                    unsigned k1 = ((unsigned)(((c0 + 1) < 64 ? cm0 : cm1) >> ((c0 + 1) & 63)) & 1u) ? ordkey(v.y) : 0xFFFFFFFFu;
                    unsigned k2 = ((unsigned)(((c0 + 2) < 64 ? cm0 : cm1) >> ((c0 + 2) & 63)) & 1u) ? ordkey(v.z) : 0xFFFFFFFFu;
                    unsigned k3 = ((unsigned)(((c0 + 3) < 64 ? cm0 : cm1) >> ((c0 + 3) & 63)) & 1u) ? ordkey(v.w) : 0xFFFFFFFFu;
                    best = u64min(best, packkrc(k0, r, c0 + 0));
                    best = u64min(best, packkrc(k1, r, c0 + 1));
                    best = u64min(best, packkrc(k2, r, c0 + 2));
                    best = u64min(best, packkrc(k3, r, c0 + 3));
                }
                // dynamic-index writeback via unrolled selects (stay in registers)
                #pragma unroll
                for (int k = 0; k < NSLOT; ++k)
                    slot[k] = (k == i) ? best : slot[k];
            }
        }
    }
}

extern "C" void kernel_launch(void* const* d_in, const int* in_sizes, int n_in,
                              void* d_out, int out_size, void* d_ws, size_t ws_size,
                              hipStream_t stream) {
    const float* logits = (const float*)d_in[0];   // [16,900,91]
    const float* pred   = (const float*)d_in[1];   // [16,900,4]
    const int*   tlab   = (const int*)d_in[2];     // [16,100]
    const float* tbox   = (const float*)d_in[3];   // [16,100,4]

    float* out = (float*)d_out;
    float* cost = out;                              // 23,040,000
    float* rows = out + (size_t)BB * QQ * BT;       // 1600
    float* cols = rows + (size_t)BB * TT;           // 1600

    cost_kernel<<<BB * QQ, NTHREADS, 0, stream>>>(logits, pred, tlab, tbox, cost);
    greedy_kernel<<<BB, NTHREADS, 0, stream>>>(cost, rows, cols);
}

// Round 5
// 263.497 us; speedup vs baseline: 19.5131x; 5.9578x over previous
//
#include <hip/hip_runtime.h>
#include <math.h>

#define BB 16
#define QQ 900
#define CC 91
#define TT 100
#define BT (BB * TT)        // 1600
#define NTHREADS 256
#define NSLOT 15            // ceil(900/64) row slots per lane

__device__ __forceinline__ unsigned ordkey(float f) {
    unsigned u = __float_as_uint(f);
    return (u & 0x80000000u) ? ~u : (u | 0x80000000u);
}

__device__ __forceinline__ unsigned long long u64min(unsigned long long a, unsigned long long b) {
    return a < b ? a : b;
}

// pack (key,row,col) -> u64; lexicographic == numpy flat-index argmin order
__device__ __forceinline__ unsigned long long packkrc(unsigned key, int row, int col) {
    return ((unsigned long long)key << 21) | ((unsigned long long)row << 11) | (unsigned)col;
}

// ---------------------------------------------------------------------------
// Kernel 1: cost[b,q,j] for j in [0, B*T)   (unchanged — verified correct)
// ---------------------------------------------------------------------------
__global__ __launch_bounds__(NTHREADS) void cost_kernel(
    const float* __restrict__ logits,
    const float* __restrict__ pred,
    const int*   __restrict__ tlab,
    const float* __restrict__ tbox,
    float*       __restrict__ cost)
{
    const int bq = blockIdx.x;
    __shared__ float sig[CC];

    const float* lg = logits + (size_t)bq * CC;
    for (int c = threadIdx.x; c < CC; c += NTHREADS) {
        float x = lg[c];
        sig[c] = 1.0f / (1.0f + expf(-x));
    }

    const float4 p = *(const float4*)(pred + (size_t)bq * 4);
    const float p_x0 = p.x - 0.5f * p.z;
    const float p_y0 = p.y - 0.5f * p.w;
    const float p_x1 = p.x + 0.5f * p.z;
    const float p_y1 = p.y + 0.5f * p.w;
    const float area1 = (p_x1 - p_x0) * (p_y1 - p_y0);

    __syncthreads();

    float* crow = cost + (size_t)bq * BT;
    for (int j = threadIdx.x; j < BT; j += NTHREADS) {
        float4 t = *(const float4*)(tbox + (size_t)j * 4);
        int id = tlab[j];
        float cclass = -sig[id];
        float cbbox = ((fabsf(p.x - t.x) + fabsf(p.y - t.y)) + fabsf(p.z - t.z)) + fabsf(p.w - t.w);

        float t_x0 = t.x - 0.5f * t.z, t_y0 = t.y - 0.5f * t.w;
        float t_x1 = t.x + 0.5f * t.z, t_y1 = t.y + 0.5f * t.w;
        float area2 = (t_x1 - t_x0) * (t_y1 - t_y0);

        float ltx = fmaxf(p_x0, t_x0), lty = fmaxf(p_y0, t_y0);
        float rbx = fminf(p_x1, t_x1), rby = fminf(p_y1, t_y1);
        float iw = fmaxf(rbx - ltx, 0.0f), ih = fmaxf(rby - lty, 0.0f);
        float inter = iw * ih;
        float uni = (area1 + area2) - inter;
        float iou = inter / uni;

        float ex0 = fminf(p_x0, t_x0), ey0 = fminf(p_y0, t_y0);
        float ex1 = fmaxf(p_x1, t_x1), ey1 = fmaxf(p_y1, t_y1);
        float ew = fmaxf(ex1 - ex0, 0.0f), eh = fmaxf(ey1 - ey0, 0.0f);
        float ae = ew * eh;
        float giou = iou - (ae - uni) / ae;

        crow[j] = (cbbox + cclass) + (-giou);
    }
}

// ---------------------------------------------------------------------------
// Kernel 2: greedy matcher, COLUMN-minima formulation.
//   State (single wave, registers): cola/colb = packed min of col lane /
//   lane+64 over valid rows; rowok = 15-bit row-validity mask per lane.
//   Per step: 1 u64min + 6-level butterfly. Rescan only when the removed
//   ROW was a column's cached argmin: expected ~6 times TOTAL (cooperative
//   64-lane strided column scan, 15 independent loads/lane).
// ---------------------------------------------------------------------------
__global__ __launch_bounds__(NTHREADS, 1) void greedy_kernel(
    const float* __restrict__ cost,
    float*       __restrict__ rows_out,
    float*       __restrict__ cols_out)
{
    const int b = blockIdx.x;
    const float* cb = cost + (size_t)b * QQ * BT;

    __shared__ unsigned long long pA[4][64];
    __shared__ unsigned long long pB[4][64];

    const int tid  = threadIdx.x;
    const int wave = tid >> 6;
    const int lane = tid & 63;

    // ---- phase 1: each wave scans 225 rows, coalesced; per-lane col minima ----
    unsigned long long minA = ~0ULL, minB = ~0ULL;
    {
        const int r0 = wave * 225;
        const int r1 = r0 + 225;
        #pragma unroll 5
        for (int r = r0; r < r1; ++r) {
            const float* row = cb + (size_t)r * BT;
            float va = row[lane];                       // cols 0..63, coalesced
            minA = u64min(minA, packkrc(ordkey(va), r, lane));
            if (lane < TT - 64) {                       // cols 64..99
                float vb = row[64 + lane];
                minB = u64min(minB, packkrc(ordkey(vb), r, 64 + lane));
            }
        }
    }
    pA[wave][lane] = minA;
    pB[wave][lane] = minB;
    __syncthreads();
    if (tid >= 64) return;          // single wave from here; no more barriers

    unsigned long long cola = u64min(u64min(pA[0][lane], pA[1][lane]),
                                     u64min(pA[2][lane], pA[3][lane]));
    unsigned long long colb = u64min(u64min(pB[0][lane], pB[1][lane]),
                                     u64min(pB[2][lane], pB[3][lane]));

    // row-validity: bits 0..13 always (r = i*64+lane <= 895); bit 14 only lanes 0..3 (896..899)
    unsigned rowok = (lane < 4) ? 0x7FFFu : 0x3FFFu;

    for (int step = 0; step < TT; ++step) {
        // ---- global argmin over 100 column minima ----
        unsigned long long m = u64min(cola, colb);
        #pragma unroll
        for (int off = 1; off < 64; off <<= 1)
            m = u64min(m, __shfl_xor(m, off, 64));

        const int rstar = (int)((m >> 11) & 0x3FF);
        const int cstar = (int)(m & 0x7FF);

        if (lane == 0) {
            rows_out[b * TT + step] = (float)rstar;
            cols_out[b * TT + step] = (float)cstar;
        }

        // remove matched column / row
        if (lane == cstar)      cola = ~0ULL;
        if (lane + 64 == cstar) colb = ~0ULL;
        if (lane == (rstar & 63)) rowok &= ~(1u << (rstar >> 6));

        // ---- columns whose cached argmin row just died (rare) ----
        unsigned long long hitsA = __ballot((int)((cola >> 11) & 0x3FF) == rstar);
        unsigned long long hitsB = __ballot((int)((colb >> 11) & 0x3FF) == rstar);

        while (hitsA | hitsB) {
            int c;
            if (hitsA) { c = (int)__ffsll((unsigned long long)hitsA) - 1;      hitsA &= hitsA - 1; }
            else       { c = (int)__ffsll((unsigned long long)hitsB) - 1 + 64; hitsB &= hitsB - 1; }

            // cooperative rescan of column c (c is wave-uniform)
            unsigned long long best = ~0ULL;
            #pragma unroll
            for (int i = 0; i < NSLOT; ++i) {
                if ((rowok >> i) & 1u) {
                    const int r = i * 64 + lane;
                    float v = cb[(size_t)r * BT + c];
                    best = u64min(best, packkrc(ordkey(v), r, c));
                }
            }
            #pragma unroll
            for (int off = 1; off < 64; off <<= 1)
                best = u64min(best, __shfl_xor(best, off, 64));

            if (lane == c)      cola = best;
            if (lane + 64 == c) colb = best;
        }
    }
}

extern "C" void kernel_launch(void* const* d_in, const int* in_sizes, int n_in,
                              void* d_out, int out_size, void* d_ws, size_t ws_size,
                              hipStream_t stream) {
    const float* logits = (const float*)d_in[0];   // [16,900,91]
    const float* pred   = (const float*)d_in[1];   // [16,900,4]
    const int*   tlab   = (const int*)d_in[2];     // [16,100]
    const float* tbox   = (const float*)d_in[3];   // [16,100,4]

    float* out = (float*)d_out;
    float* cost = out;                              // 23,040,000
    float* rows = out + (size_t)BB * QQ * BT;       // 1600
    float* cols = rows + (size_t)BB * TT;           // 1600

    cost_kernel<<<BB * QQ, NTHREADS, 0, stream>>>(logits, pred, tlab, tbox, cost);
    greedy_kernel<<<BB, NTHREADS, 0, stream>>>(cost, rows, cols);
}